// Round 10
// baseline (3449.282 us; speedup 1.0000x reference)
//
#include <hip/hip_runtime.h>

using u32 = unsigned int;
using s64 = long long;

// -------- int width detection (int64 iff hi-words of first 64 entries all 0) --------
__global__ __launch_bounds__(64) void k_detect10(const u32* __restrict__ ei,
                                                 const u32* __restrict__ nt,
                                                 const u32* __restrict__ tp,
                                                 u32* __restrict__ flags) {
    if (blockIdx.x != 0 || threadIdx.x != 0) return;
    bool e64 = true, n64 = true, t64 = true;
    for (int k = 0; k < 64; ++k) {
        if (ei[2 * k + 1] != 0u) e64 = false;
        if (nt[2 * k + 1] != 0u) n64 = false;
        if (tp[2 * k + 1] != 0u) t64 = false;
    }
    flags[0] = e64 ? 1u : 0u;
    flags[1] = n64 ? 1u : 0u;
    flags[2] = t64 ? 1u : 0u;
}

// -------- width-adaptive convert to int32 --------
__global__ __launch_bounds__(256) void k_cvt10(const void* __restrict__ src,
                                               int* __restrict__ dst, long long n,
                                               const u32* __restrict__ flags, int fidx) {
    long long i = (long long)blockIdx.x * 256 + threadIdx.x;
    if (i >= n) return;
    dst[i] = flags[fidx] ? (int)((const s64*)src)[i] : ((const int*)src)[i];
}

// ---------------- zero ----------------
__global__ __launch_bounds__(256) void kz10(float* __restrict__ p, long long n) {
    long long i = (long long)blockIdx.x * 256 + threadIdx.x;
    if (i < n) p[i] = 0.f;
}

// ---------------- QKV: one 64-thread block per node ----------------
__global__ __launch_bounds__(64) void k_qkv10(const float* __restrict__ x,
                                              const float* __restrict__ Wq,
                                              const float* __restrict__ Wk,
                                              const float* __restrict__ Wv,
                                              float* __restrict__ big) {
    int i = blockIdx.x, j = threadIdx.x;
    float q0 = 0.f, q1 = 0.f, kk0 = 0.f, kk1 = 0.f, v0 = 0.f, v1 = 0.f;
    for (int k = 0; k < 128; ++k) {
        float xa = x[(size_t)i * 128 + k];
        q0  += xa * Wq[k * 128 + j];
        q1  += xa * Wq[k * 128 + 64 + j];
        kk0 += xa * Wk[k * 128 + j];
        kk1 += xa * Wk[k * 128 + 64 + j];
        v0  += xa * Wv[k * 128 + j];
        v1  += xa * Wv[k * 128 + 64 + j];
    }
    size_t b = (size_t)i * 384;
    big[b + j] = q0;        big[b + 64 + j] = q1;
    big[b + 128 + j] = kk0; big[b + 192 + j] = kk1;
    big[b + 256 + j] = v0;  big[b + 320 + j] = v1;
}

// ---------------- GAT softmax denominator ----------------
__global__ __launch_bounds__(256) void k_gat_sm10(const float* __restrict__ big,
                                                  const int* __restrict__ ei, int E,
                                                  float* __restrict__ sm) {
    long long t = (long long)blockIdx.x * 256 + threadIdx.x;
    if (t >= (long long)E * 8) return;
    int e = (int)(t >> 3), h = (int)(t & 7);
    int row = ei[e], col = ei[E + e];
    float s = 0.f;
    for (int d = 0; d < 16; ++d)
        s += big[(size_t)row * 384 + h * 16 + d] * big[(size_t)col * 384 + 128 + h * 16 + d];
    s *= 0.25f;                   // 1/sqrt(16)
    s = s > 0.f ? s : 0.2f * s;   // leaky_relu before segment softmax
    atomicAdd(&sm[(size_t)col * 8 + h], expf(s));   // shift-free softmax (|s| small)
}

// ---------------- GAT weighted-V scatter ----------------
__global__ __launch_bounds__(256) void k_gat_wv10(const float* __restrict__ big,
                                                  const int* __restrict__ ei, int E,
                                                  const float* __restrict__ sm,
                                                  float* __restrict__ agg) {
    long long t = (long long)blockIdx.x * 256 + threadIdx.x;
    if (t >= (long long)E * 128) return;
    int e = (int)(t >> 7), j = (int)(t & 127);
    int row = ei[e], col = ei[E + e];
    int h = j >> 4;
    float s = 0.f;                // identical FP sequence to k_gat_sm10
    for (int d = 0; d < 16; ++d)
        s += big[(size_t)row * 384 + h * 16 + d] * big[(size_t)col * 384 + 128 + h * 16 + d];
    s *= 0.25f;
    s = s > 0.f ? s : 0.2f * s;
    float p = expf(s) / sm[(size_t)col * 8 + h];
    atomicAdd(&agg[(size_t)col * 128 + j], p * big[(size_t)row * 384 + 256 + j]);
}

// ---------------- GAT epilogue: obr = LN(agg@Wo + bo + x) ----------------
__global__ __launch_bounds__(64) void k_ep_gat10(const float* __restrict__ x,
                                                 const float* __restrict__ agg,
                                                 const float* __restrict__ Wo,
                                                 const float* __restrict__ bo,
                                                 const float* __restrict__ g,
                                                 const float* __restrict__ b,
                                                 float* __restrict__ obr) {
    __shared__ float buf[130];
    int i = blockIdx.x, j = threadIdx.x;
    float a0 = bo[j], a1 = bo[64 + j];
    for (int k = 0; k < 128; ++k) {
        float ak = agg[(size_t)i * 128 + k];
        a0 += ak * Wo[k * 128 + j];
        a1 += ak * Wo[k * 128 + 64 + j];
    }
    float v0 = a0 + x[(size_t)i * 128 + j];
    float v1 = a1 + x[(size_t)i * 128 + 64 + j];
    buf[j] = v0; buf[64 + j] = v1;
    __syncthreads();
    if (j == 0) {
        float s = 0.f;
        for (int k = 0; k < 128; ++k) s += buf[k];
        float m = s * 0.0078125f;
        float var = 0.f;
        for (int k = 0; k < 128; ++k) { float d = buf[k] - m; var += d * d; }
        buf[128] = m; buf[129] = rsqrtf(var * 0.0078125f + 1e-5f);
    }
    __syncthreads();
    float m = buf[128], r = buf[129];
    obr[(size_t)i * 128 + j]      = (v0 - m) * r * g[j]      + b[j];
    obr[(size_t)i * 128 + 64 + j] = (v1 - m) * r * g[64 + j] + b[64 + j];
}

// ---------------- per-type transform: h_gcn = x@Wt[t] + bt[t] ----------------
__global__ __launch_bounds__(64) void k_hgcn10(const float* __restrict__ x,
                                               const int* __restrict__ nt,
                                               const float* __restrict__ Wt,
                                               const float* __restrict__ bt,
                                               float* __restrict__ h_gcn) {
    int i = blockIdx.x, j = threadIdx.x;
    int t = nt[i];
    t = (t < 0 || t > 5) ? 0 : t;
    const float* W = Wt + (size_t)t * 16384;
    float a0 = bt[t * 128 + j], a1 = bt[t * 128 + 64 + j];
    for (int k = 0; k < 128; ++k) {
        float xa = x[(size_t)i * 128 + k];
        a0 += xa * W[k * 128 + j];
        a1 += xa * W[k * 128 + 64 + j];
    }
    h_gcn[(size_t)i * 128 + j] = a0;
    h_gcn[(size_t)i * 128 + 64 + j] = a1;
}

// ---------------- edge MLP: agg[col] += relu([h[row],h[col]]@W1+b1)@W2+b2 ----------------
__global__ __launch_bounds__(64) void k_mlp_edge10(const float* __restrict__ hsrc,
                                                   const float* __restrict__ x,
                                                   const float* __restrict__ emb,
                                                   const int* __restrict__ tpos,
                                                   const int* __restrict__ ei, int E, int mode,
                                                   const float* __restrict__ W1,
                                                   const float* __restrict__ b1,
                                                   const float* __restrict__ W2,
                                                   const float* __restrict__ b2,
                                                   float* __restrict__ agg) {
    __shared__ float m1[128];
    int e = blockIdx.x, j = threadIdx.x;
    int row = ei[e], col = ei[E + e];
    int tpr = 0, tpc = 0;
    if (mode) {
        tpr = tpos[row]; tpr = tpr < 0 ? 0 : (tpr > 49 ? 49 : tpr);
        tpc = tpos[col]; tpc = tpc < 0 ? 0 : (tpc > 49 ? 49 : tpc);
    }
    float a0 = b1[j], a1 = b1[64 + j];
    for (int k = 0; k < 128; ++k) {
        float hr = mode ? (x[(size_t)row * 128 + k] + emb[tpr * 128 + k])
                        : hsrc[(size_t)row * 128 + k];
        float hc = mode ? (x[(size_t)col * 128 + k] + emb[tpc * 128 + k])
                        : hsrc[(size_t)col * 128 + k];
        a0 += hr * W1[k * 128 + j]      + hc * W1[(128 + k) * 128 + j];
        a1 += hr * W1[k * 128 + 64 + j] + hc * W1[(128 + k) * 128 + 64 + j];
    }
    m1[j] = a0 > 0.f ? a0 : 0.f;
    m1[64 + j] = a1 > 0.f ? a1 : 0.f;
    __syncthreads();
    float o0 = b2[j], o1 = b2[64 + j];
    for (int k = 0; k < 128; ++k) {
        float mk = m1[k];
        o0 += mk * W2[k * 128 + j];
        o1 += mk * W2[k * 128 + 64 + j];
    }
    atomicAdd(&agg[(size_t)col * 128 + j], o0);
    atomicAdd(&agg[(size_t)col * 128 + 64 + j], o1);
}

// ---------------- GCN epilogue ----------------
__global__ __launch_bounds__(64) void k_ep_gcn10(const float* __restrict__ x,
                                                 const float* __restrict__ h_gcn,
                                                 const float* __restrict__ agg,
                                                 const float* __restrict__ aW1,
                                                 const float* __restrict__ ab1,
                                                 const float* __restrict__ aW2,
                                                 const float* __restrict__ ab2,
                                                 const float* __restrict__ Wo,
                                                 const float* __restrict__ bo,
                                                 const float* __restrict__ g,
                                                 const float* __restrict__ b,
                                                 float* __restrict__ obr) {
    __shared__ float u[128];
    __shared__ float z3[128];
    __shared__ float buf[130];
    int i = blockIdx.x, j = threadIdx.x;
    float a0 = ab1[j], a1 = ab1[64 + j];
    for (int k = 0; k < 128; ++k) {
        float ak = agg[(size_t)i * 128 + k];
        a0 += ak * aW1[k * 128 + j];
        a1 += ak * aW1[k * 128 + 64 + j];
    }
    u[j] = a0 > 0.f ? a0 : 0.f;
    u[64 + j] = a1 > 0.f ? a1 : 0.f;
    __syncthreads();
    float c0 = ab2[j], c1 = ab2[64 + j];
    for (int k = 0; k < 128; ++k) {
        float uk = u[k];
        c0 += uk * aW2[k * 128 + j];
        c1 += uk * aW2[k * 128 + 64 + j];
    }
    z3[j] = c0 + h_gcn[(size_t)i * 128 + j];
    z3[64 + j] = c1 + h_gcn[(size_t)i * 128 + 64 + j];
    __syncthreads();
    float d0 = bo[j], d1 = bo[64 + j];
    for (int k = 0; k < 128; ++k) {
        float zk = z3[k];
        d0 += zk * Wo[k * 128 + j];
        d1 += zk * Wo[k * 128 + 64 + j];
    }
    float v0 = d0 + x[(size_t)i * 128 + j];
    float v1 = d1 + x[(size_t)i * 128 + 64 + j];
    buf[j] = v0; buf[64 + j] = v1;
    __syncthreads();
    if (j == 0) {
        float s = 0.f;
        for (int k = 0; k < 128; ++k) s += buf[k];
        float m = s * 0.0078125f;
        float var = 0.f;
        for (int k = 0; k < 128; ++k) { float d = buf[k] - m; var += d * d; }
        buf[128] = m; buf[129] = rsqrtf(var * 0.0078125f + 1e-5f);
    }
    __syncthreads();
    float m = buf[128], r = buf[129];
    obr[(size_t)i * 128 + j]      = (v0 - m) * r * g[j]      + b[j];
    obr[(size_t)i * 128 + 64 + j] = (v1 - m) * r * g[64 + j] + b[64 + j];
}

// ---------------- temporal epilogue ----------------
__global__ __launch_bounds__(64) void k_ep_tmp10(const float* __restrict__ x,
                                                 const float* __restrict__ emb,
                                                 const int* __restrict__ tpos,
                                                 const float* __restrict__ agg,
                                                 const float* __restrict__ Wo,
                                                 const float* __restrict__ bo,
                                                 const float* __restrict__ g,
                                                 const float* __restrict__ b,
                                                 float* __restrict__ obr) {
    __shared__ float z[128];
    __shared__ float buf[130];
    int i = blockIdx.x, j = threadIdx.x;
    int tp = tpos[i]; tp = tp < 0 ? 0 : (tp > 49 ? 49 : tp);
    z[j]      = x[(size_t)i * 128 + j]      + emb[tp * 128 + j]      + agg[(size_t)i * 128 + j];
    z[64 + j] = x[(size_t)i * 128 + 64 + j] + emb[tp * 128 + 64 + j] + agg[(size_t)i * 128 + 64 + j];
    __syncthreads();
    float a0 = bo[j], a1 = bo[64 + j];
    for (int k = 0; k < 128; ++k) {
        float zk = z[k];
        a0 += zk * Wo[k * 128 + j];
        a1 += zk * Wo[k * 128 + 64 + j];
    }
    buf[j] = a0; buf[64 + j] = a1;
    __syncthreads();
    if (j == 0) {
        float s = 0.f;
        for (int k = 0; k < 128; ++k) s += buf[k];
        float m = s * 0.0078125f;
        float var = 0.f;
        for (int k = 0; k < 128; ++k) { float d = buf[k] - m; var += d * d; }
        buf[128] = m; buf[129] = rsqrtf(var * 0.0078125f + 1e-5f);
    }
    __syncthreads();
    float m = buf[128], r = buf[129];
    obr[(size_t)i * 128 + j]      = (a0 - m) * r * g[j]      + b[j];
    obr[(size_t)i * 128 + 64 + j] = (a1 - m) * r * g[64 + j] + b[64 + j];
}

// ---------------- fusion accumulate ----------------
__global__ __launch_bounds__(64) void k_fuse10(const float* __restrict__ obr,
                                               const float* __restrict__ fusW,
                                               const float* __restrict__ fus_b,
                                               float* __restrict__ fused, int off, int first) {
    int i = blockIdx.x, j = threadIdx.x;
    float a0 = first ? fus_b[j]      : fused[(size_t)i * 128 + j];
    float a1 = first ? fus_b[64 + j] : fused[(size_t)i * 128 + 64 + j];
    for (int k = 0; k < 128; ++k) {
        float ok = obr[(size_t)i * 128 + k];
        a0 += ok * fusW[(size_t)(off + k) * 128 + j];
        a1 += ok * fusW[(size_t)(off + k) * 128 + 64 + j];
    }
    fused[(size_t)i * 128 + j] = a0;
    fused[(size_t)i * 128 + 64 + j] = a1;
}

// ---------------- final LN -> FLOAT32 out ----------------
__global__ __launch_bounds__(64) void k_final10(const float* __restrict__ fused,
                                                const float* __restrict__ g,
                                                const float* __restrict__ b,
                                                float* __restrict__ out) {
    __shared__ float buf[130];
    int i = blockIdx.x, j = threadIdx.x;
    float v0 = fused[(size_t)i * 128 + j];
    float v1 = fused[(size_t)i * 128 + 64 + j];
    buf[j] = v0; buf[64 + j] = v1;
    __syncthreads();
    if (j == 0) {
        float s = 0.f;
        for (int k = 0; k < 128; ++k) s += buf[k];
        float m = s * 0.0078125f;
        float var = 0.f;
        for (int k = 0; k < 128; ++k) { float d = buf[k] - m; var += d * d; }
        buf[128] = m; buf[129] = rsqrtf(var * 0.0078125f + 1e-5f);
    }
    __syncthreads();
    float m = buf[128], r = buf[129];
    out[(size_t)i * 128 + j]      = (v0 - m) * r * g[j]      + b[j];
    out[(size_t)i * 128 + 64 + j] = (v1 - m) * r * g[64 + j] + b[64 + j];
}

extern "C" void kernel_launch(void* const* d_in, const int* in_sizes, int n_in, void* d_out,
                              int out_size, void* d_ws, size_t ws_size, hipStream_t stream) {
    (void)n_in; (void)out_size; (void)ws_size;
    const float* x = (const float*)d_in[0];
    const float* gat_Wq = (const float*)d_in[4];
    const float* gat_Wk = (const float*)d_in[5];
    const float* gat_Wv = (const float*)d_in[6];
    const float* gat_Wo = (const float*)d_in[7];
    const float* gat_bo = (const float*)d_in[8];
    const float* gat_g = (const float*)d_in[9];
    const float* gat_b = (const float*)d_in[10];
    const float* gcn_Wt = (const float*)d_in[11];
    const float* gcn_bt = (const float*)d_in[12];
    const float* gcn_mW1 = (const float*)d_in[13];
    const float* gcn_mb1 = (const float*)d_in[14];
    const float* gcn_mW2 = (const float*)d_in[15];
    const float* gcn_mb2 = (const float*)d_in[16];
    const float* gcn_aW1 = (const float*)d_in[17];
    const float* gcn_ab1 = (const float*)d_in[18];
    const float* gcn_aW2 = (const float*)d_in[19];
    const float* gcn_ab2 = (const float*)d_in[20];
    const float* gcn_Wo = (const float*)d_in[21];
    const float* gcn_bo = (const float*)d_in[22];
    const float* gcn_g = (const float*)d_in[23];
    const float* gcn_b = (const float*)d_in[24];
    const float* tmp_emb = (const float*)d_in[25];
    const float* tmp_W1 = (const float*)d_in[26];
    const float* tmp_b1 = (const float*)d_in[27];
    const float* tmp_W2 = (const float*)d_in[28];
    const float* tmp_b2 = (const float*)d_in[29];
    const float* tmp_Wo = (const float*)d_in[30];
    const float* tmp_bo = (const float*)d_in[31];
    const float* tmp_g = (const float*)d_in[32];
    const float* tmp_b = (const float*)d_in[33];
    const float* fus_W = (const float*)d_in[34];
    const float* fus_b = (const float*)d_in[35];
    const float* fus_g = (const float*)d_in[36];
    const float* fus_be = (const float*)d_in[37];

    int N = in_sizes[0] / 128;
    int E = in_sizes[1] / 2;

    // ---- workspace: 648N floats | flags u32[16] | ei32[2E] | nt32[N] | tp32[N] ----
    float* ws = (float*)d_ws;
    float* big = ws;                          // [0,384N): QKV during GAT phase
    float* fused = ws;                        // [0,128N): alias after QKV dead
    float* h_gcn = ws + (size_t)128 * N;      // [128N,256N): alias after QKV dead
    float* obr = ws + (size_t)384 * N;        // [384N,512N)
    float* agg = ws + (size_t)512 * N;        // [512N,640N)
    float* sm = ws + (size_t)640 * N;         // [640N,648N)
    u32* flags = (u32*)(ws + (size_t)648 * N);
    int* ei32 = (int*)(flags + 16);
    int* nt32 = ei32 + (size_t)2 * E;
    int* tp32 = nt32 + N;

    // ---- index canonicalization (planar (2,E) layout — same bytes+shape as np ref) ----
    k_detect10<<<1, 64, 0, stream>>>((const u32*)d_in[1], (const u32*)d_in[2],
                                     (const u32*)d_in[3], flags);
    long long nEI = (long long)2 * E;
    k_cvt10<<<(int)((nEI + 255) / 256), 256, 0, stream>>>(d_in[1], ei32, nEI, flags, 0);
    k_cvt10<<<(N + 255) / 256, 256, 0, stream>>>(d_in[2], nt32, N, flags, 1);
    k_cvt10<<<(N + 255) / 256, 256, 0, stream>>>(d_in[3], tp32, N, flags, 2);

    long long nAgg = (long long)128 * N, nAggSm = (long long)136 * N;
    int gAggSm = (int)((nAggSm + 255) / 256), gAgg = (int)((nAgg + 255) / 256);
    int gE8 = (int)(((long long)E * 8 + 255) / 256);
    int gE128 = (int)(((long long)E * 128 + 255) / 256);

    // ===== GAT branch =====
    kz10<<<gAggSm, 256, 0, stream>>>(agg, nAggSm);                   // zero agg + sm
    k_qkv10<<<N, 64, 0, stream>>>(x, gat_Wq, gat_Wk, gat_Wv, big);
    k_gat_sm10<<<gE8, 256, 0, stream>>>(big, ei32, E, sm);
    k_gat_wv10<<<gE128, 256, 0, stream>>>(big, ei32, E, sm, agg);
    k_ep_gat10<<<N, 64, 0, stream>>>(x, agg, gat_Wo, gat_bo, gat_g, gat_b, obr);
    k_fuse10<<<N, 64, 0, stream>>>(obr, fus_W, fus_b, fused, 0, 1);  // QKV dead; overwrite OK

    // ===== GCN branch =====
    k_hgcn10<<<N, 64, 0, stream>>>(x, nt32, gcn_Wt, gcn_bt, h_gcn);
    kz10<<<gAgg, 256, 0, stream>>>(agg, nAgg);
    k_mlp_edge10<<<E, 64, 0, stream>>>(h_gcn, x, tmp_emb, tp32, ei32, E, 0,
                                       gcn_mW1, gcn_mb1, gcn_mW2, gcn_mb2, agg);
    k_ep_gcn10<<<N, 64, 0, stream>>>(x, h_gcn, agg, gcn_aW1, gcn_ab1, gcn_aW2, gcn_ab2,
                                     gcn_Wo, gcn_bo, gcn_g, gcn_b, obr);
    k_fuse10<<<N, 64, 0, stream>>>(obr, fus_W, fus_b, fused, 128, 0);

    // ===== temporal branch =====
    kz10<<<gAgg, 256, 0, stream>>>(agg, nAgg);
    k_mlp_edge10<<<E, 64, 0, stream>>>(nullptr, x, tmp_emb, tp32, ei32, E, 1,
                                       tmp_W1, tmp_b1, tmp_W2, tmp_b2, agg);
    k_ep_tmp10<<<N, 64, 0, stream>>>(x, tmp_emb, tp32, agg, tmp_Wo, tmp_bo, tmp_g, tmp_b, obr);
    k_fuse10<<<N, 64, 0, stream>>>(obr, fus_W, fus_b, fused, 256, 0);

    // ===== final (FLOAT32 output) =====
    k_final10<<<N, 64, 0, stream>>>(fused, fus_g, fus_be, (float*)d_out);
}

// Round 11
// 2547.160 us; speedup vs baseline: 1.3542x; 1.3542x over previous
//
#include <hip/hip_runtime.h>

using u32 = unsigned int;
using s64 = long long;

// -------- int width detection (int64 iff hi-words of first 64 entries all 0) --------
__global__ __launch_bounds__(64) void k_detect11(const u32* __restrict__ ei,
                                                 const u32* __restrict__ nt,
                                                 const u32* __restrict__ tp,
                                                 u32* __restrict__ flags) {
    if (blockIdx.x != 0 || threadIdx.x != 0) return;
    bool e64 = true, n64 = true, t64 = true;
    for (int k = 0; k < 64; ++k) {
        if (ei[2 * k + 1] != 0u) e64 = false;
        if (nt[2 * k + 1] != 0u) n64 = false;
        if (tp[2 * k + 1] != 0u) t64 = false;
    }
    flags[0] = e64 ? 1u : 0u;
    flags[1] = n64 ? 1u : 0u;
    flags[2] = t64 ? 1u : 0u;
}

// -------- width-adaptive convert to int32 --------
__global__ __launch_bounds__(256) void k_cvt11(const void* __restrict__ src,
                                               int* __restrict__ dst, long long n,
                                               const u32* __restrict__ flags, int fidx) {
    long long i = (long long)blockIdx.x * 256 + threadIdx.x;
    if (i >= n) return;
    dst[i] = flags[fidx] ? (int)((const s64*)src)[i] : ((const int*)src)[i];
}

// ---------------- zero ----------------
__global__ __launch_bounds__(256) void kz11(float* __restrict__ p, long long n) {
    long long i = (long long)blockIdx.x * 256 + threadIdx.x;
    if (i < n) p[i] = 0.f;
}

// ---------------- QKV: one 64-thread block per node ----------------
__global__ __launch_bounds__(64) void k_qkv11(const float* __restrict__ x,
                                              const float* __restrict__ Wq,
                                              const float* __restrict__ Wk,
                                              const float* __restrict__ Wv,
                                              float* __restrict__ big) {
    int i = blockIdx.x, j = threadIdx.x;
    float q0 = 0.f, q1 = 0.f, kk0 = 0.f, kk1 = 0.f, v0 = 0.f, v1 = 0.f;
    for (int k = 0; k < 128; ++k) {
        float xa = x[(size_t)i * 128 + k];
        q0  += xa * Wq[k * 128 + j];
        q1  += xa * Wq[k * 128 + 64 + j];
        kk0 += xa * Wk[k * 128 + j];
        kk1 += xa * Wk[k * 128 + 64 + j];
        v0  += xa * Wv[k * 128 + j];
        v1  += xa * Wv[k * 128 + 64 + j];
    }
    size_t b = (size_t)i * 384;
    big[b + j] = q0;        big[b + 64 + j] = q1;
    big[b + 128 + j] = kk0; big[b + 192 + j] = kk1;
    big[b + 256 + j] = v0;  big[b + 320 + j] = v1;
}

// ---------------- GAT softmax denominator ----------------
__global__ __launch_bounds__(256) void k_gat_sm11(const float* __restrict__ big,
                                                  const int* __restrict__ ei, int E,
                                                  float* __restrict__ sm) {
    long long t = (long long)blockIdx.x * 256 + threadIdx.x;
    if (t >= (long long)E * 8) return;
    int e = (int)(t >> 3), h = (int)(t & 7);
    int row = ei[e], col = ei[E + e];
    float s = 0.f;
    for (int d = 0; d < 16; ++d)
        s += big[(size_t)row * 384 + h * 16 + d] * big[(size_t)col * 384 + 128 + h * 16 + d];
    s *= 0.25f;
    s = s > 0.f ? s : 0.2f * s;
    atomicAdd(&sm[(size_t)col * 8 + h], expf(s));
}

// ---------------- GAT weighted-V scatter ----------------
__global__ __launch_bounds__(256) void k_gat_wv11(const float* __restrict__ big,
                                                  const int* __restrict__ ei, int E,
                                                  const float* __restrict__ sm,
                                                  float* __restrict__ agg) {
    long long t = (long long)blockIdx.x * 256 + threadIdx.x;
    if (t >= (long long)E * 128) return;
    int e = (int)(t >> 7), j = (int)(t & 127);
    int row = ei[e], col = ei[E + e];
    int h = j >> 4;
    float s = 0.f;                // identical FP sequence to k_gat_sm11
    for (int d = 0; d < 16; ++d)
        s += big[(size_t)row * 384 + h * 16 + d] * big[(size_t)col * 384 + 128 + h * 16 + d];
    s *= 0.25f;
    s = s > 0.f ? s : 0.2f * s;
    float p = expf(s) / sm[(size_t)col * 8 + h];
    atomicAdd(&agg[(size_t)col * 128 + j], p * big[(size_t)row * 384 + 256 + j]);
}

// ---------------- GAT epilogue: obr = LN(agg@Wo + bo + x) ----------------
__global__ __launch_bounds__(64) void k_ep_gat11(const float* __restrict__ x,
                                                 const float* __restrict__ agg,
                                                 const float* __restrict__ Wo,
                                                 const float* __restrict__ bo,
                                                 const float* __restrict__ g,
                                                 const float* __restrict__ b,
                                                 float* __restrict__ obr) {
    __shared__ float buf[130];
    int i = blockIdx.x, j = threadIdx.x;
    float a0 = bo[j], a1 = bo[64 + j];
    for (int k = 0; k < 128; ++k) {
        float ak = agg[(size_t)i * 128 + k];
        a0 += ak * Wo[k * 128 + j];
        a1 += ak * Wo[k * 128 + 64 + j];
    }
    float v0 = a0 + x[(size_t)i * 128 + j];
    float v1 = a1 + x[(size_t)i * 128 + 64 + j];
    buf[j] = v0; buf[64 + j] = v1;
    __syncthreads();
    if (j == 0) {
        float s = 0.f;
        for (int k = 0; k < 128; ++k) s += buf[k];
        float m = s * 0.0078125f;
        float var = 0.f;
        for (int k = 0; k < 128; ++k) { float d = buf[k] - m; var += d * d; }
        buf[128] = m; buf[129] = rsqrtf(var * 0.0078125f + 1e-5f);
    }
    __syncthreads();
    float m = buf[128], r = buf[129];
    obr[(size_t)i * 128 + j]      = (v0 - m) * r * g[j]      + b[j];
    obr[(size_t)i * 128 + 64 + j] = (v1 - m) * r * g[64 + j] + b[64 + j];
}

// ---------------- per-type transform: h_gcn = x@Wt[t] + bt[t] ----------------
__global__ __launch_bounds__(64) void k_hgcn11(const float* __restrict__ x,
                                               const int* __restrict__ nt,
                                               const float* __restrict__ Wt,
                                               const float* __restrict__ bt,
                                               float* __restrict__ h_gcn) {
    int i = blockIdx.x, j = threadIdx.x;
    int t = nt[i];
    t = (t < 0 || t > 5) ? 0 : t;
    const float* W = Wt + (size_t)t * 16384;
    float a0 = bt[t * 128 + j], a1 = bt[t * 128 + 64 + j];
    for (int k = 0; k < 128; ++k) {
        float xa = x[(size_t)i * 128 + k];
        a0 += xa * W[k * 128 + j];
        a1 += xa * W[k * 128 + 64 + j];
    }
    h_gcn[(size_t)i * 128 + j] = a0;
    h_gcn[(size_t)i * 128 + 64 + j] = a1;
}

// ---------------- h_tmp = x + emb[clip(tpos)] ----------------
__global__ __launch_bounds__(256) void k_htmp11(const float* __restrict__ x,
                                                const float* __restrict__ emb,
                                                const int* __restrict__ tpos,
                                                float* __restrict__ h_tmp, int N) {
    long long t = (long long)blockIdx.x * 256 + threadIdx.x;
    if (t >= (long long)N * 128) return;
    int i = (int)(t >> 7), j = (int)(t & 127);
    int tp = tpos[i]; tp = tp < 0 ? 0 : (tp > 49 ? 49 : tp);
    h_tmp[t] = x[t] + emb[tp * 128 + j];
}

// ------- edge MLP (wave-batched): agg[col] += relu([h[row],h[col]]@W1+b1)@W2+b2 -------
// 256-thread blocks = 4 waves; each wave handles 4 edges per iteration.
// Broadcast layout: zr[n][c] on lane l = z[c*64+l]; lane l accumulates out[l], out[64+l].
__global__ __launch_bounds__(256) void k_mlp_edge11(const float* __restrict__ h,
                                                    const int* __restrict__ ei, int E,
                                                    const float* __restrict__ W1,
                                                    const float* __restrict__ b1,
                                                    const float* __restrict__ W2,
                                                    const float* __restrict__ b2,
                                                    float* __restrict__ agg) {
    __shared__ float w1s[16384];  // W1 rows 0..127 (64 KB): the h[row] half of K
    for (int i = threadIdx.x; i < 16384; i += 256) w1s[i] = W1[i];
    __syncthreads();
    int l = threadIdx.x & 63;
    int wid = blockIdx.x * 4 + (threadIdx.x >> 6);
    int nw = gridDim.x * 4;
    float b1v0 = b1[l], b1v1 = b1[64 + l];
    float b2v0 = b2[l], b2v1 = b2[64 + l];
    for (int e0 = wid * 4; e0 < E; e0 += nw * 4) {
        int ne = E - e0; if (ne > 4) ne = 4;
        int colv[4];
        float zr[4][4];
#pragma unroll
        for (int n = 0; n < 4; ++n) {
            int e = e0 + ((n < ne) ? n : 0);
            int row = ei[e], col = ei[E + e];
            colv[n] = col;
            zr[n][0] = h[(size_t)row * 128 + l];
            zr[n][1] = h[(size_t)row * 128 + 64 + l];
            zr[n][2] = h[(size_t)col * 128 + l];
            zr[n][3] = h[(size_t)col * 128 + 64 + l];
        }
        float acc[4][2];
#pragma unroll
        for (int n = 0; n < 4; ++n) { acc[n][0] = b1v0; acc[n][1] = b1v1; }
        // layer 1: K=256. c=0,1 (h[row] features) from LDS; c=2,3 (h[col]) from L2.
#pragma unroll
        for (int c = 0; c < 4; ++c) {
#pragma unroll 8
            for (int k2 = 0; k2 < 64; ++k2) {
                int k = c * 64 + k2;
                float w0, w1v;
                if (c < 2) { w0 = w1s[k * 128 + l];          w1v = w1s[k * 128 + 64 + l]; }
                else       { w0 = W1[(size_t)k * 128 + l];   w1v = W1[(size_t)k * 128 + 64 + l]; }
#pragma unroll
                for (int n = 0; n < 4; ++n) {
                    float xk = __shfl(zr[n][c], k2);
                    acc[n][0] = fmaf(xk, w0, acc[n][0]);
                    acc[n][1] = fmaf(xk, w1v, acc[n][1]);
                }
            }
        }
        // relu (output already in broadcast layout: acc[n][0]=m[l], acc[n][1]=m[64+l])
        float z2[4][2];
#pragma unroll
        for (int n = 0; n < 4; ++n) {
            z2[n][0] = acc[n][0] > 0.f ? acc[n][0] : 0.f;
            z2[n][1] = acc[n][1] > 0.f ? acc[n][1] : 0.f;
        }
        float acc2[4][2];
#pragma unroll
        for (int n = 0; n < 4; ++n) { acc2[n][0] = b2v0; acc2[n][1] = b2v1; }
        // layer 2: K=128 from L2-resident W2
#pragma unroll
        for (int c = 0; c < 2; ++c) {
#pragma unroll 8
            for (int k2 = 0; k2 < 64; ++k2) {
                int k = c * 64 + k2;
                float w0 = W2[(size_t)k * 128 + l];
                float w1v = W2[(size_t)k * 128 + 64 + l];
#pragma unroll
                for (int n = 0; n < 4; ++n) {
                    float xk = __shfl(z2[n][c], k2);
                    acc2[n][0] = fmaf(xk, w0, acc2[n][0]);
                    acc2[n][1] = fmaf(xk, w1v, acc2[n][1]);
                }
            }
        }
#pragma unroll
        for (int n = 0; n < 4; ++n) {
            if (n < ne) {
                atomicAdd(&agg[(size_t)colv[n] * 128 + l], acc2[n][0]);
                atomicAdd(&agg[(size_t)colv[n] * 128 + 64 + l], acc2[n][1]);
            }
        }
    }
}

// ---------------- GCN epilogue ----------------
__global__ __launch_bounds__(64) void k_ep_gcn11(const float* __restrict__ x,
                                                 const float* __restrict__ h_gcn,
                                                 const float* __restrict__ agg,
                                                 const float* __restrict__ aW1,
                                                 const float* __restrict__ ab1,
                                                 const float* __restrict__ aW2,
                                                 const float* __restrict__ ab2,
                                                 const float* __restrict__ Wo,
                                                 const float* __restrict__ bo,
                                                 const float* __restrict__ g,
                                                 const float* __restrict__ b,
                                                 float* __restrict__ obr) {
    __shared__ float u[128];
    __shared__ float z3[128];
    __shared__ float buf[130];
    int i = blockIdx.x, j = threadIdx.x;
    float a0 = ab1[j], a1 = ab1[64 + j];
    for (int k = 0; k < 128; ++k) {
        float ak = agg[(size_t)i * 128 + k];
        a0 += ak * aW1[k * 128 + j];
        a1 += ak * aW1[k * 128 + 64 + j];
    }
    u[j] = a0 > 0.f ? a0 : 0.f;
    u[64 + j] = a1 > 0.f ? a1 : 0.f;
    __syncthreads();
    float c0 = ab2[j], c1 = ab2[64 + j];
    for (int k = 0; k < 128; ++k) {
        float uk = u[k];
        c0 += uk * aW2[k * 128 + j];
        c1 += uk * aW2[k * 128 + 64 + j];
    }
    z3[j] = c0 + h_gcn[(size_t)i * 128 + j];
    z3[64 + j] = c1 + h_gcn[(size_t)i * 128 + 64 + j];
    __syncthreads();
    float d0 = bo[j], d1 = bo[64 + j];
    for (int k = 0; k < 128; ++k) {
        float zk = z3[k];
        d0 += zk * Wo[k * 128 + j];
        d1 += zk * Wo[k * 128 + 64 + j];
    }
    float v0 = d0 + x[(size_t)i * 128 + j];
    float v1 = d1 + x[(size_t)i * 128 + 64 + j];
    buf[j] = v0; buf[64 + j] = v1;
    __syncthreads();
    if (j == 0) {
        float s = 0.f;
        for (int k = 0; k < 128; ++k) s += buf[k];
        float m = s * 0.0078125f;
        float var = 0.f;
        for (int k = 0; k < 128; ++k) { float d = buf[k] - m; var += d * d; }
        buf[128] = m; buf[129] = rsqrtf(var * 0.0078125f + 1e-5f);
    }
    __syncthreads();
    float m = buf[128], r = buf[129];
    obr[(size_t)i * 128 + j]      = (v0 - m) * r * g[j]      + b[j];
    obr[(size_t)i * 128 + 64 + j] = (v1 - m) * r * g[64 + j] + b[64 + j];
}

// ---------------- temporal epilogue: obr = LN((h_tmp+agg)@Wo + bo) ----------------
__global__ __launch_bounds__(64) void k_ep_tmp11(const float* __restrict__ h_tmp,
                                                 const float* __restrict__ agg,
                                                 const float* __restrict__ Wo,
                                                 const float* __restrict__ bo,
                                                 const float* __restrict__ g,
                                                 const float* __restrict__ b,
                                                 float* __restrict__ obr) {
    __shared__ float z[128];
    __shared__ float buf[130];
    int i = blockIdx.x, j = threadIdx.x;
    z[j]      = h_tmp[(size_t)i * 128 + j]      + agg[(size_t)i * 128 + j];
    z[64 + j] = h_tmp[(size_t)i * 128 + 64 + j] + agg[(size_t)i * 128 + 64 + j];
    __syncthreads();
    float a0 = bo[j], a1 = bo[64 + j];
    for (int k = 0; k < 128; ++k) {
        float zk = z[k];
        a0 += zk * Wo[k * 128 + j];
        a1 += zk * Wo[k * 128 + 64 + j];
    }
    buf[j] = a0; buf[64 + j] = a1;
    __syncthreads();
    if (j == 0) {
        float s = 0.f;
        for (int k = 0; k < 128; ++k) s += buf[k];
        float m = s * 0.0078125f;
        float var = 0.f;
        for (int k = 0; k < 128; ++k) { float d = buf[k] - m; var += d * d; }
        buf[128] = m; buf[129] = rsqrtf(var * 0.0078125f + 1e-5f);
    }
    __syncthreads();
    float m = buf[128], r = buf[129];
    obr[(size_t)i * 128 + j]      = (a0 - m) * r * g[j]      + b[j];
    obr[(size_t)i * 128 + 64 + j] = (a1 - m) * r * g[64 + j] + b[64 + j];
}

// ---------------- fusion accumulate ----------------
__global__ __launch_bounds__(64) void k_fuse11(const float* __restrict__ obr,
                                               const float* __restrict__ fusW,
                                               const float* __restrict__ fus_b,
                                               float* __restrict__ fused, int off, int first) {
    int i = blockIdx.x, j = threadIdx.x;
    float a0 = first ? fus_b[j]      : fused[(size_t)i * 128 + j];
    float a1 = first ? fus_b[64 + j] : fused[(size_t)i * 128 + 64 + j];
    for (int k = 0; k < 128; ++k) {
        float ok = obr[(size_t)i * 128 + k];
        a0 += ok * fusW[(size_t)(off + k) * 128 + j];
        a1 += ok * fusW[(size_t)(off + k) * 128 + 64 + j];
    }
    fused[(size_t)i * 128 + j] = a0;
    fused[(size_t)i * 128 + 64 + j] = a1;
}

// ---------------- final LN -> float32 out ----------------
__global__ __launch_bounds__(64) void k_final11(const float* __restrict__ fused,
                                                const float* __restrict__ g,
                                                const float* __restrict__ b,
                                                float* __restrict__ out) {
    __shared__ float buf[130];
    int i = blockIdx.x, j = threadIdx.x;
    float v0 = fused[(size_t)i * 128 + j];
    float v1 = fused[(size_t)i * 128 + 64 + j];
    buf[j] = v0; buf[64 + j] = v1;
    __syncthreads();
    if (j == 0) {
        float s = 0.f;
        for (int k = 0; k < 128; ++k) s += buf[k];
        float m = s * 0.0078125f;
        float var = 0.f;
        for (int k = 0; k < 128; ++k) { float d = buf[k] - m; var += d * d; }
        buf[128] = m; buf[129] = rsqrtf(var * 0.0078125f + 1e-5f);
    }
    __syncthreads();
    float m = buf[128], r = buf[129];
    out[(size_t)i * 128 + j]      = (v0 - m) * r * g[j]      + b[j];
    out[(size_t)i * 128 + 64 + j] = (v1 - m) * r * g[64 + j] + b[64 + j];
}

extern "C" void kernel_launch(void* const* d_in, const int* in_sizes, int n_in, void* d_out,
                              int out_size, void* d_ws, size_t ws_size, hipStream_t stream) {
    (void)n_in; (void)out_size; (void)ws_size;
    const float* x = (const float*)d_in[0];
    const float* gat_Wq = (const float*)d_in[4];
    const float* gat_Wk = (const float*)d_in[5];
    const float* gat_Wv = (const float*)d_in[6];
    const float* gat_Wo = (const float*)d_in[7];
    const float* gat_bo = (const float*)d_in[8];
    const float* gat_g = (const float*)d_in[9];
    const float* gat_b = (const float*)d_in[10];
    const float* gcn_Wt = (const float*)d_in[11];
    const float* gcn_bt = (const float*)d_in[12];
    const float* gcn_mW1 = (const float*)d_in[13];
    const float* gcn_mb1 = (const float*)d_in[14];
    const float* gcn_mW2 = (const float*)d_in[15];
    const float* gcn_mb2 = (const float*)d_in[16];
    const float* gcn_aW1 = (const float*)d_in[17];
    const float* gcn_ab1 = (const float*)d_in[18];
    const float* gcn_aW2 = (const float*)d_in[19];
    const float* gcn_ab2 = (const float*)d_in[20];
    const float* gcn_Wo = (const float*)d_in[21];
    const float* gcn_bo = (const float*)d_in[22];
    const float* gcn_g = (const float*)d_in[23];
    const float* gcn_b = (const float*)d_in[24];
    const float* tmp_emb = (const float*)d_in[25];
    const float* tmp_W1 = (const float*)d_in[26];
    const float* tmp_b1 = (const float*)d_in[27];
    const float* tmp_W2 = (const float*)d_in[28];
    const float* tmp_b2 = (const float*)d_in[29];
    const float* tmp_Wo = (const float*)d_in[30];
    const float* tmp_bo = (const float*)d_in[31];
    const float* tmp_g = (const float*)d_in[32];
    const float* tmp_b = (const float*)d_in[33];
    const float* fus_W = (const float*)d_in[34];
    const float* fus_b = (const float*)d_in[35];
    const float* fus_g = (const float*)d_in[36];
    const float* fus_be = (const float*)d_in[37];

    int N = in_sizes[0] / 128;
    int E = in_sizes[1] / 2;

    // ---- workspace: 648N floats | flags u32[16] | ei32[2E] | nt32[N] | tp32[N] ----
    float* ws = (float*)d_ws;
    float* big = ws;                          // [0,384N): QKV during GAT phase
    float* fused = ws;                        // [0,128N): alias after QKV dead
    float* h_gcn = ws + (size_t)128 * N;      // [128N,256N): alias after QKV dead
    float* h_tmp = ws + (size_t)256 * N;      // [256N,384N): alias after QKV dead
    float* obr = ws + (size_t)384 * N;        // [384N,512N)
    float* agg = ws + (size_t)512 * N;        // [512N,640N)
    float* sm = ws + (size_t)640 * N;         // [640N,648N)
    u32* flags = (u32*)(ws + (size_t)648 * N);
    int* ei32 = (int*)(flags + 16);
    int* nt32 = ei32 + (size_t)2 * E;
    int* tp32 = nt32 + N;

    // ---- index canonicalization (planar (2,E) layout) ----
    k_detect11<<<1, 64, 0, stream>>>((const u32*)d_in[1], (const u32*)d_in[2],
                                     (const u32*)d_in[3], flags);
    long long nEI = (long long)2 * E;
    k_cvt11<<<(int)((nEI + 255) / 256), 256, 0, stream>>>(d_in[1], ei32, nEI, flags, 0);
    k_cvt11<<<(N + 255) / 256, 256, 0, stream>>>(d_in[2], nt32, N, flags, 1);
    k_cvt11<<<(N + 255) / 256, 256, 0, stream>>>(d_in[3], tp32, N, flags, 2);

    long long nAgg = (long long)128 * N, nAggSm = (long long)136 * N;
    int gAggSm = (int)((nAggSm + 255) / 256), gAgg = (int)((nAgg + 255) / 256);
    int gE8 = (int)(((long long)E * 8 + 255) / 256);
    int gE128 = (int)(((long long)E * 128 + 255) / 256);
    int gN128 = (int)(((long long)N * 128 + 255) / 256);

    // ===== GAT branch =====
    kz11<<<gAggSm, 256, 0, stream>>>(agg, nAggSm);                   // zero agg + sm
    k_qkv11<<<N, 64, 0, stream>>>(x, gat_Wq, gat_Wk, gat_Wv, big);
    k_gat_sm11<<<gE8, 256, 0, stream>>>(big, ei32, E, sm);
    k_gat_wv11<<<gE128, 256, 0, stream>>>(big, ei32, E, sm, agg);
    k_ep_gat11<<<N, 64, 0, stream>>>(x, agg, gat_Wo, gat_bo, gat_g, gat_b, obr);
    k_fuse11<<<N, 64, 0, stream>>>(obr, fus_W, fus_b, fused, 0, 1);  // QKV dead; overwrite OK

    // ===== GCN branch =====
    k_hgcn11<<<N, 64, 0, stream>>>(x, nt32, gcn_Wt, gcn_bt, h_gcn);
    kz11<<<gAgg, 256, 0, stream>>>(agg, nAgg);
    k_mlp_edge11<<<512, 256, 0, stream>>>(h_gcn, ei32, E, gcn_mW1, gcn_mb1, gcn_mW2, gcn_mb2, agg);
    k_ep_gcn11<<<N, 64, 0, stream>>>(x, h_gcn, agg, gcn_aW1, gcn_ab1, gcn_aW2, gcn_ab2,
                                     gcn_Wo, gcn_bo, gcn_g, gcn_b, obr);
    k_fuse11<<<N, 64, 0, stream>>>(obr, fus_W, fus_b, fused, 128, 0);

    // ===== temporal branch =====
    k_htmp11<<<gN128, 256, 0, stream>>>(x, tmp_emb, tp32, h_tmp, N);
    kz11<<<gAgg, 256, 0, stream>>>(agg, nAgg);
    k_mlp_edge11<<<512, 256, 0, stream>>>(h_tmp, ei32, E, tmp_W1, tmp_b1, tmp_W2, tmp_b2, agg);
    k_ep_tmp11<<<N, 64, 0, stream>>>(h_tmp, agg, tmp_Wo, tmp_bo, tmp_g, tmp_b, obr);
    k_fuse11<<<N, 64, 0, stream>>>(obr, fus_W, fus_b, fused, 256, 0);

    // ===== final (float32 output) =====
    k_final11<<<N, 64, 0, stream>>>(fused, fus_g, fus_be, (float*)d_out);
}

// Round 12
// 2542.892 us; speedup vs baseline: 1.3564x; 1.0017x over previous
//
#include <hip/hip_runtime.h>

using u32 = unsigned int;
using s64 = long long;

// -------- int width detection (int64 iff hi-words of first 64 entries all 0) --------
__global__ __launch_bounds__(64) void k_detect12(const u32* __restrict__ ei,
                                                 const u32* __restrict__ nt,
                                                 const u32* __restrict__ tp,
                                                 u32* __restrict__ flags) {
    if (blockIdx.x != 0 || threadIdx.x != 0) return;
    bool e64 = true, n64 = true, t64 = true;
    for (int k = 0; k < 64; ++k) {
        if (ei[2 * k + 1] != 0u) e64 = false;
        if (nt[2 * k + 1] != 0u) n64 = false;
        if (tp[2 * k + 1] != 0u) t64 = false;
    }
    flags[0] = e64 ? 1u : 0u;
    flags[1] = n64 ? 1u : 0u;
    flags[2] = t64 ? 1u : 0u;
}

// -------- width-adaptive convert to int32 --------
__global__ __launch_bounds__(256) void k_cvt12(const void* __restrict__ src,
                                               int* __restrict__ dst, long long n,
                                               const u32* __restrict__ flags, int fidx) {
    long long i = (long long)blockIdx.x * 256 + threadIdx.x;
    if (i >= n) return;
    dst[i] = flags[fidx] ? (int)((const s64*)src)[i] : ((const int*)src)[i];
}

// ---------------- zero ----------------
__global__ __launch_bounds__(256) void kz12(float* __restrict__ p, long long n) {
    long long i = (long long)blockIdx.x * 256 + threadIdx.x;
    if (i < n) p[i] = 0.f;
}

// ---------------- QKV: one 64-thread block per node ----------------
__global__ __launch_bounds__(64) void k_qkv12(const float* __restrict__ x,
                                              const float* __restrict__ Wq,
                                              const float* __restrict__ Wk,
                                              const float* __restrict__ Wv,
                                              float* __restrict__ big) {
    int i = blockIdx.x, j = threadIdx.x;
    float q0 = 0.f, q1 = 0.f, kk0 = 0.f, kk1 = 0.f, v0 = 0.f, v1 = 0.f;
    for (int k = 0; k < 128; ++k) {
        float xa = x[(size_t)i * 128 + k];
        q0  += xa * Wq[k * 128 + j];
        q1  += xa * Wq[k * 128 + 64 + j];
        kk0 += xa * Wk[k * 128 + j];
        kk1 += xa * Wk[k * 128 + 64 + j];
        v0  += xa * Wv[k * 128 + j];
        v1  += xa * Wv[k * 128 + 64 + j];
    }
    size_t b = (size_t)i * 384;
    big[b + j] = q0;        big[b + 64 + j] = q1;
    big[b + 128 + j] = kk0; big[b + 192 + j] = kk1;
    big[b + 256 + j] = v0;  big[b + 320 + j] = v1;
}

// ---------------- GAT scores: store exp + segment denominator ----------------
__global__ __launch_bounds__(256) void k_gat_sm12(const float* __restrict__ big,
                                                  const int* __restrict__ ei, int E,
                                                  float* __restrict__ scores,
                                                  float* __restrict__ sm) {
    long long t = (long long)blockIdx.x * 256 + threadIdx.x;
    if (t >= (long long)E * 8) return;
    int e = (int)(t >> 3), h = (int)(t & 7);
    int row = ei[e], col = ei[E + e];
    float s = 0.f;
    for (int d = 0; d < 16; ++d)
        s += big[(size_t)row * 384 + h * 16 + d] * big[(size_t)col * 384 + 128 + h * 16 + d];
    s *= 0.25f;
    s = s > 0.f ? s : 0.2f * s;
    float ex = expf(s);
    scores[t] = ex;
    atomicAdd(&sm[(size_t)col * 8 + h], ex);
}

// ---------------- GAT weighted-V scatter (reads stored probs) ----------------
__global__ __launch_bounds__(256) void k_gat_wv12(const float* __restrict__ big,
                                                  const int* __restrict__ ei, int E,
                                                  const float* __restrict__ scores,
                                                  const float* __restrict__ sm,
                                                  float* __restrict__ agg) {
    long long t = (long long)blockIdx.x * 256 + threadIdx.x;
    if (t >= (long long)E * 128) return;
    int e = (int)(t >> 7), j = (int)(t & 127);
    int row = ei[e], col = ei[E + e];
    int h = j >> 4;
    float p = scores[(size_t)e * 8 + h] / sm[(size_t)col * 8 + h];
    atomicAdd(&agg[(size_t)col * 128 + j], p * big[(size_t)row * 384 + 256 + j]);
}

// ---------------- GAT epilogue: obr = LN(agg@Wo + bo + x) ----------------
__global__ __launch_bounds__(64) void k_ep_gat12(const float* __restrict__ x,
                                                 const float* __restrict__ agg,
                                                 const float* __restrict__ Wo,
                                                 const float* __restrict__ bo,
                                                 const float* __restrict__ g,
                                                 const float* __restrict__ b,
                                                 float* __restrict__ obr) {
    __shared__ float buf[130];
    int i = blockIdx.x, j = threadIdx.x;
    float a0 = bo[j], a1 = bo[64 + j];
    for (int k = 0; k < 128; ++k) {
        float ak = agg[(size_t)i * 128 + k];
        a0 += ak * Wo[k * 128 + j];
        a1 += ak * Wo[k * 128 + 64 + j];
    }
    float v0 = a0 + x[(size_t)i * 128 + j];
    float v1 = a1 + x[(size_t)i * 128 + 64 + j];
    buf[j] = v0; buf[64 + j] = v1;
    __syncthreads();
    if (j == 0) {
        float s = 0.f;
        for (int k = 0; k < 128; ++k) s += buf[k];
        float m = s * 0.0078125f;
        float var = 0.f;
        for (int k = 0; k < 128; ++k) { float d = buf[k] - m; var += d * d; }
        buf[128] = m; buf[129] = rsqrtf(var * 0.0078125f + 1e-5f);
    }
    __syncthreads();
    float m = buf[128], r = buf[129];
    obr[(size_t)i * 128 + j]      = (v0 - m) * r * g[j]      + b[j];
    obr[(size_t)i * 128 + 64 + j] = (v1 - m) * r * g[64 + j] + b[64 + j];
}

// ---------------- per-type transform: h_gcn = x@Wt[t] + bt[t] ----------------
__global__ __launch_bounds__(64) void k_hgcn12(const float* __restrict__ x,
                                               const int* __restrict__ nt,
                                               const float* __restrict__ Wt,
                                               const float* __restrict__ bt,
                                               float* __restrict__ h_gcn) {
    int i = blockIdx.x, j = threadIdx.x;
    int t = nt[i];
    t = (t < 0 || t > 5) ? 0 : t;
    const float* W = Wt + (size_t)t * 16384;
    float a0 = bt[t * 128 + j], a1 = bt[t * 128 + 64 + j];
    for (int k = 0; k < 128; ++k) {
        float xa = x[(size_t)i * 128 + k];
        a0 += xa * W[k * 128 + j];
        a1 += xa * W[k * 128 + 64 + j];
    }
    h_gcn[(size_t)i * 128 + j] = a0;
    h_gcn[(size_t)i * 128 + 64 + j] = a1;
}

// ---------------- h_tmp = x + emb[clip(tpos)] ----------------
__global__ __launch_bounds__(256) void k_htmp12(const float* __restrict__ x,
                                                const float* __restrict__ emb,
                                                const int* __restrict__ tpos,
                                                float* __restrict__ h_tmp, int N) {
    long long t = (long long)blockIdx.x * 256 + threadIdx.x;
    if (t >= (long long)N * 128) return;
    int i = (int)(t >> 7), j = (int)(t & 127);
    int tp = tpos[i]; tp = tp < 0 ? 0 : (tp > 49 ? 49 : tp);
    h_tmp[t] = x[t] + emb[tp * 128 + j];
}

// ------- edge MLP (wave-batched): agg[col] += relu([h[row],h[col]]@W1+b1)@W2+b2 -------
// 512-thread blocks = 8 waves sharing one 64 KB W1 stage -> 2 blocks/CU = 16 waves/CU.
__global__ __launch_bounds__(512) void k_mlp_edge12(const float* __restrict__ h,
                                                    const int* __restrict__ ei, int E,
                                                    const float* __restrict__ W1,
                                                    const float* __restrict__ b1,
                                                    const float* __restrict__ W2,
                                                    const float* __restrict__ b2,
                                                    float* __restrict__ agg) {
    __shared__ float w1s[16384];  // W1 rows 0..127 (64 KB): the h[row] half of K
    for (int i = threadIdx.x; i < 16384; i += 512) w1s[i] = W1[i];
    __syncthreads();
    int l = threadIdx.x & 63;
    int wid = blockIdx.x * 8 + (threadIdx.x >> 6);
    int nw = gridDim.x * 8;
    float b1v0 = b1[l], b1v1 = b1[64 + l];
    float b2v0 = b2[l], b2v1 = b2[64 + l];
    for (int e0 = wid * 4; e0 < E; e0 += nw * 4) {
        int ne = E - e0; if (ne > 4) ne = 4;
        int colv[4];
        float zr[4][4];
#pragma unroll
        for (int n = 0; n < 4; ++n) {
            int e = e0 + ((n < ne) ? n : 0);
            int row = ei[e], col = ei[E + e];
            colv[n] = col;
            zr[n][0] = h[(size_t)row * 128 + l];
            zr[n][1] = h[(size_t)row * 128 + 64 + l];
            zr[n][2] = h[(size_t)col * 128 + l];
            zr[n][3] = h[(size_t)col * 128 + 64 + l];
        }
        float acc[4][2];
#pragma unroll
        for (int n = 0; n < 4; ++n) { acc[n][0] = b1v0; acc[n][1] = b1v1; }
        // layer 1: K=256. c=0,1 (h[row] features) from LDS; c=2,3 (h[col]) from L2.
#pragma unroll
        for (int c = 0; c < 4; ++c) {
#pragma unroll 8
            for (int k2 = 0; k2 < 64; ++k2) {
                int k = c * 64 + k2;
                float w0, w1v;
                if (c < 2) { w0 = w1s[k * 128 + l];          w1v = w1s[k * 128 + 64 + l]; }
                else       { w0 = W1[(size_t)k * 128 + l];   w1v = W1[(size_t)k * 128 + 64 + l]; }
#pragma unroll
                for (int n = 0; n < 4; ++n) {
                    float xk = __shfl(zr[n][c], k2);
                    acc[n][0] = fmaf(xk, w0, acc[n][0]);
                    acc[n][1] = fmaf(xk, w1v, acc[n][1]);
                }
            }
        }
        float z2[4][2];
#pragma unroll
        for (int n = 0; n < 4; ++n) {
            z2[n][0] = acc[n][0] > 0.f ? acc[n][0] : 0.f;
            z2[n][1] = acc[n][1] > 0.f ? acc[n][1] : 0.f;
        }
        float acc2[4][2];
#pragma unroll
        for (int n = 0; n < 4; ++n) { acc2[n][0] = b2v0; acc2[n][1] = b2v1; }
        // layer 2: K=128 from L2-resident W2
#pragma unroll
        for (int c = 0; c < 2; ++c) {
#pragma unroll 8
            for (int k2 = 0; k2 < 64; ++k2) {
                int k = c * 64 + k2;
                float w0 = W2[(size_t)k * 128 + l];
                float w1v = W2[(size_t)k * 128 + 64 + l];
#pragma unroll
                for (int n = 0; n < 4; ++n) {
                    float xk = __shfl(z2[n][c], k2);
                    acc2[n][0] = fmaf(xk, w0, acc2[n][0]);
                    acc2[n][1] = fmaf(xk, w1v, acc2[n][1]);
                }
            }
        }
#pragma unroll
        for (int n = 0; n < 4; ++n) {
            if (n < ne) {
                atomicAdd(&agg[(size_t)colv[n] * 128 + l], acc2[n][0]);
                atomicAdd(&agg[(size_t)colv[n] * 128 + 64 + l], acc2[n][1]);
            }
        }
    }
}

// ---------------- GCN epilogue ----------------
__global__ __launch_bounds__(64) void k_ep_gcn12(const float* __restrict__ x,
                                                 const float* __restrict__ h_gcn,
                                                 const float* __restrict__ agg,
                                                 const float* __restrict__ aW1,
                                                 const float* __restrict__ ab1,
                                                 const float* __restrict__ aW2,
                                                 const float* __restrict__ ab2,
                                                 const float* __restrict__ Wo,
                                                 const float* __restrict__ bo,
                                                 const float* __restrict__ g,
                                                 const float* __restrict__ b,
                                                 float* __restrict__ obr) {
    __shared__ float u[128];
    __shared__ float z3[128];
    __shared__ float buf[130];
    int i = blockIdx.x, j = threadIdx.x;
    float a0 = ab1[j], a1 = ab1[64 + j];
    for (int k = 0; k < 128; ++k) {
        float ak = agg[(size_t)i * 128 + k];
        a0 += ak * aW1[k * 128 + j];
        a1 += ak * aW1[k * 128 + 64 + j];
    }
    u[j] = a0 > 0.f ? a0 : 0.f;
    u[64 + j] = a1 > 0.f ? a1 : 0.f;
    __syncthreads();
    float c0 = ab2[j], c1 = ab2[64 + j];
    for (int k = 0; k < 128; ++k) {
        float uk = u[k];
        c0 += uk * aW2[k * 128 + j];
        c1 += uk * aW2[k * 128 + 64 + j];
    }
    z3[j] = c0 + h_gcn[(size_t)i * 128 + j];
    z3[64 + j] = c1 + h_gcn[(size_t)i * 128 + 64 + j];
    __syncthreads();
    float d0 = bo[j], d1 = bo[64 + j];
    for (int k = 0; k < 128; ++k) {
        float zk = z3[k];
        d0 += zk * Wo[k * 128 + j];
        d1 += zk * Wo[k * 128 + 64 + j];
    }
    float v0 = d0 + x[(size_t)i * 128 + j];
    float v1 = d1 + x[(size_t)i * 128 + 64 + j];
    buf[j] = v0; buf[64 + j] = v1;
    __syncthreads();
    if (j == 0) {
        float s = 0.f;
        for (int k = 0; k < 128; ++k) s += buf[k];
        float m = s * 0.0078125f;
        float var = 0.f;
        for (int k = 0; k < 128; ++k) { float d = buf[k] - m; var += d * d; }
        buf[128] = m; buf[129] = rsqrtf(var * 0.0078125f + 1e-5f);
    }
    __syncthreads();
    float m = buf[128], r = buf[129];
    obr[(size_t)i * 128 + j]      = (v0 - m) * r * g[j]      + b[j];
    obr[(size_t)i * 128 + 64 + j] = (v1 - m) * r * g[64 + j] + b[64 + j];
}

// ---------------- temporal epilogue ----------------
__global__ __launch_bounds__(64) void k_ep_tmp12(const float* __restrict__ h_tmp,
                                                 const float* __restrict__ agg,
                                                 const float* __restrict__ Wo,
                                                 const float* __restrict__ bo,
                                                 const float* __restrict__ g,
                                                 const float* __restrict__ b,
                                                 float* __restrict__ obr) {
    __shared__ float z[128];
    __shared__ float buf[130];
    int i = blockIdx.x, j = threadIdx.x;
    z[j]      = h_tmp[(size_t)i * 128 + j]      + agg[(size_t)i * 128 + j];
    z[64 + j] = h_tmp[(size_t)i * 128 + 64 + j] + agg[(size_t)i * 128 + 64 + j];
    __syncthreads();
    float a0 = bo[j], a1 = bo[64 + j];
    for (int k = 0; k < 128; ++k) {
        float zk = z[k];
        a0 += zk * Wo[k * 128 + j];
        a1 += zk * Wo[k * 128 + 64 + j];
    }
    buf[j] = a0; buf[64 + j] = a1;
    __syncthreads();
    if (j == 0) {
        float s = 0.f;
        for (int k = 0; k < 128; ++k) s += buf[k];
        float m = s * 0.0078125f;
        float var = 0.f;
        for (int k = 0; k < 128; ++k) { float d = buf[k] - m; var += d * d; }
        buf[128] = m; buf[129] = rsqrtf(var * 0.0078125f + 1e-5f);
    }
    __syncthreads();
    float m = buf[128], r = buf[129];
    obr[(size_t)i * 128 + j]      = (a0 - m) * r * g[j]      + b[j];
    obr[(size_t)i * 128 + 64 + j] = (a1 - m) * r * g[64 + j] + b[64 + j];
}

// ---------------- fusion accumulate ----------------
__global__ __launch_bounds__(64) void k_fuse12(const float* __restrict__ obr,
                                               const float* __restrict__ fusW,
                                               const float* __restrict__ fus_b,
                                               float* __restrict__ fused, int off, int first) {
    int i = blockIdx.x, j = threadIdx.x;
    float a0 = first ? fus_b[j]      : fused[(size_t)i * 128 + j];
    float a1 = first ? fus_b[64 + j] : fused[(size_t)i * 128 + 64 + j];
    for (int k = 0; k < 128; ++k) {
        float ok = obr[(size_t)i * 128 + k];
        a0 += ok * fusW[(size_t)(off + k) * 128 + j];
        a1 += ok * fusW[(size_t)(off + k) * 128 + 64 + j];
    }
    fused[(size_t)i * 128 + j] = a0;
    fused[(size_t)i * 128 + 64 + j] = a1;
}

// ---------------- final LN -> float32 out ----------------
__global__ __launch_bounds__(64) void k_final12(const float* __restrict__ fused,
                                                const float* __restrict__ g,
                                                const float* __restrict__ b,
                                                float* __restrict__ out) {
    __shared__ float buf[130];
    int i = blockIdx.x, j = threadIdx.x;
    float v0 = fused[(size_t)i * 128 + j];
    float v1 = fused[(size_t)i * 128 + 64 + j];
    buf[j] = v0; buf[64 + j] = v1;
    __syncthreads();
    if (j == 0) {
        float s = 0.f;
        for (int k = 0; k < 128; ++k) s += buf[k];
        float m = s * 0.0078125f;
        float var = 0.f;
        for (int k = 0; k < 128; ++k) { float d = buf[k] - m; var += d * d; }
        buf[128] = m; buf[129] = rsqrtf(var * 0.0078125f + 1e-5f);
    }
    __syncthreads();
    float m = buf[128], r = buf[129];
    out[(size_t)i * 128 + j]      = (v0 - m) * r * g[j]      + b[j];
    out[(size_t)i * 128 + 64 + j] = (v1 - m) * r * g[64 + j] + b[64 + j];
}

extern "C" void kernel_launch(void* const* d_in, const int* in_sizes, int n_in, void* d_out,
                              int out_size, void* d_ws, size_t ws_size, hipStream_t stream) {
    (void)n_in; (void)out_size; (void)ws_size;
    const float* x = (const float*)d_in[0];
    const float* gat_Wq = (const float*)d_in[4];
    const float* gat_Wk = (const float*)d_in[5];
    const float* gat_Wv = (const float*)d_in[6];
    const float* gat_Wo = (const float*)d_in[7];
    const float* gat_bo = (const float*)d_in[8];
    const float* gat_g = (const float*)d_in[9];
    const float* gat_b = (const float*)d_in[10];
    const float* gcn_Wt = (const float*)d_in[11];
    const float* gcn_bt = (const float*)d_in[12];
    const float* gcn_mW1 = (const float*)d_in[13];
    const float* gcn_mb1 = (const float*)d_in[14];
    const float* gcn_mW2 = (const float*)d_in[15];
    const float* gcn_mb2 = (const float*)d_in[16];
    const float* gcn_aW1 = (const float*)d_in[17];
    const float* gcn_ab1 = (const float*)d_in[18];
    const float* gcn_aW2 = (const float*)d_in[19];
    const float* gcn_ab2 = (const float*)d_in[20];
    const float* gcn_Wo = (const float*)d_in[21];
    const float* gcn_bo = (const float*)d_in[22];
    const float* gcn_g = (const float*)d_in[23];
    const float* gcn_b = (const float*)d_in[24];
    const float* tmp_emb = (const float*)d_in[25];
    const float* tmp_W1 = (const float*)d_in[26];
    const float* tmp_b1 = (const float*)d_in[27];
    const float* tmp_W2 = (const float*)d_in[28];
    const float* tmp_b2 = (const float*)d_in[29];
    const float* tmp_Wo = (const float*)d_in[30];
    const float* tmp_bo = (const float*)d_in[31];
    const float* tmp_g = (const float*)d_in[32];
    const float* tmp_b = (const float*)d_in[33];
    const float* fus_W = (const float*)d_in[34];
    const float* fus_b = (const float*)d_in[35];
    const float* fus_g = (const float*)d_in[36];
    const float* fus_be = (const float*)d_in[37];

    int N = in_sizes[0] / 128;
    int E = in_sizes[1] / 2;

    // ---- workspace ----
    float* ws = (float*)d_ws;
    float* big = ws;                          // [0,384N): QKV during GAT phase
    float* fused = ws;                        // [0,128N): alias after QKV dead
    float* h_gcn = ws + (size_t)128 * N;      // [128N,256N): alias after QKV dead
    float* h_tmp = ws + (size_t)256 * N;      // [256N,384N): alias after QKV dead
    float* obr = ws + (size_t)384 * N;        // [384N,512N)
    float* agg = ws + (size_t)512 * N;        // [512N,640N)
    float* sm = ws + (size_t)640 * N;         // [640N,648N)
    u32* flags = (u32*)(ws + (size_t)648 * N);
    int* ei32 = (int*)(flags + 16);
    int* nt32 = ei32 + (size_t)2 * E;
    int* tp32 = nt32 + N;
    float* scores = (float*)(tp32 + N);       // E*8 floats

    // ---- index canonicalization (planar (2,E) layout) ----
    k_detect12<<<1, 64, 0, stream>>>((const u32*)d_in[1], (const u32*)d_in[2],
                                     (const u32*)d_in[3], flags);
    long long nEI = (long long)2 * E;
    k_cvt12<<<(int)((nEI + 255) / 256), 256, 0, stream>>>(d_in[1], ei32, nEI, flags, 0);
    k_cvt12<<<(N + 255) / 256, 256, 0, stream>>>(d_in[2], nt32, N, flags, 1);
    k_cvt12<<<(N + 255) / 256, 256, 0, stream>>>(d_in[3], tp32, N, flags, 2);

    long long nAgg = (long long)128 * N, nAggSm = (long long)136 * N;
    int gAggSm = (int)((nAggSm + 255) / 256), gAgg = (int)((nAgg + 255) / 256);
    int gE8 = (int)(((long long)E * 8 + 255) / 256);
    int gE128 = (int)(((long long)E * 128 + 255) / 256);
    int gN128 = (int)(((long long)N * 128 + 255) / 256);

    // ===== GAT branch =====
    kz12<<<gAggSm, 256, 0, stream>>>(agg, nAggSm);                   // zero agg + sm
    k_qkv12<<<N, 64, 0, stream>>>(x, gat_Wq, gat_Wk, gat_Wv, big);
    k_gat_sm12<<<gE8, 256, 0, stream>>>(big, ei32, E, scores, sm);
    k_gat_wv12<<<gE128, 256, 0, stream>>>(big, ei32, E, scores, sm, agg);
    k_ep_gat12<<<N, 64, 0, stream>>>(x, agg, gat_Wo, gat_bo, gat_g, gat_b, obr);
    k_fuse12<<<N, 64, 0, stream>>>(obr, fus_W, fus_b, fused, 0, 1);  // QKV dead; overwrite OK

    // ===== GCN branch =====
    k_hgcn12<<<N, 64, 0, stream>>>(x, nt32, gcn_Wt, gcn_bt, h_gcn);
    kz12<<<gAgg, 256, 0, stream>>>(agg, nAgg);
    k_mlp_edge12<<<256, 512, 0, stream>>>(h_gcn, ei32, E, gcn_mW1, gcn_mb1, gcn_mW2, gcn_mb2, agg);
    k_ep_gcn12<<<N, 64, 0, stream>>>(x, h_gcn, agg, gcn_aW1, gcn_ab1, gcn_aW2, gcn_ab2,
                                     gcn_Wo, gcn_bo, gcn_g, gcn_b, obr);
    k_fuse12<<<N, 64, 0, stream>>>(obr, fus_W, fus_b, fused, 128, 0);

    // ===== temporal branch =====
    k_htmp12<<<gN128, 256, 0, stream>>>(x, tmp_emb, tp32, h_tmp, N);
    kz12<<<gAgg, 256, 0, stream>>>(agg, nAgg);
    k_mlp_edge12<<<256, 512, 0, stream>>>(h_tmp, ei32, E, tmp_W1, tmp_b1, tmp_W2, tmp_b2, agg);
    k_ep_tmp12<<<N, 64, 0, stream>>>(h_tmp, agg, tmp_Wo, tmp_bo, tmp_g, tmp_b, obr);
    k_fuse12<<<N, 64, 0, stream>>>(obr, fus_W, fus_b, fused, 256, 0);

    // ===== final (float32 output) =====
    k_final12<<<N, 64, 0, stream>>>(fused, fus_g, fus_be, (float*)d_out);
}

// Round 13
// 2506.972 us; speedup vs baseline: 1.3759x; 1.0143x over previous
//
#include <hip/hip_runtime.h>

using u32 = unsigned int;
using s64 = long long;

// -------- int width detection (int64 iff hi-words of first 64 entries all 0) --------
__global__ __launch_bounds__(64) void k_detect13(const u32* __restrict__ ei,
                                                 const u32* __restrict__ nt,
                                                 const u32* __restrict__ tp,
                                                 u32* __restrict__ flags) {
    if (blockIdx.x != 0 || threadIdx.x != 0) return;
    bool e64 = true, n64 = true, t64 = true;
    for (int k = 0; k < 64; ++k) {
        if (ei[2 * k + 1] != 0u) e64 = false;
        if (nt[2 * k + 1] != 0u) n64 = false;
        if (tp[2 * k + 1] != 0u) t64 = false;
    }
    flags[0] = e64 ? 1u : 0u;
    flags[1] = n64 ? 1u : 0u;
    flags[2] = t64 ? 1u : 0u;
}

// -------- width-adaptive convert to int32 --------
__global__ __launch_bounds__(256) void k_cvt13(const void* __restrict__ src,
                                               int* __restrict__ dst, long long n,
                                               const u32* __restrict__ flags, int fidx) {
    long long i = (long long)blockIdx.x * 256 + threadIdx.x;
    if (i >= n) return;
    dst[i] = flags[fidx] ? (int)((const s64*)src)[i] : ((const int*)src)[i];
}

// ---------------- zero ----------------
__global__ __launch_bounds__(256) void kz13(float* __restrict__ p, long long n) {
    long long i = (long long)blockIdx.x * 256 + threadIdx.x;
    if (i < n) p[i] = 0.f;
}

// ---------------- QKV: one 64-thread block per node ----------------
__global__ __launch_bounds__(64) void k_qkv13(const float* __restrict__ x,
                                              const float* __restrict__ Wq,
                                              const float* __restrict__ Wk,
                                              const float* __restrict__ Wv,
                                              float* __restrict__ big) {
    int i = blockIdx.x, j = threadIdx.x;
    float q0 = 0.f, q1 = 0.f, kk0 = 0.f, kk1 = 0.f, v0 = 0.f, v1 = 0.f;
    for (int k = 0; k < 128; ++k) {
        float xa = x[(size_t)i * 128 + k];
        q0  += xa * Wq[k * 128 + j];
        q1  += xa * Wq[k * 128 + 64 + j];
        kk0 += xa * Wk[k * 128 + j];
        kk1 += xa * Wk[k * 128 + 64 + j];
        v0  += xa * Wv[k * 128 + j];
        v1  += xa * Wv[k * 128 + 64 + j];
    }
    size_t b = (size_t)i * 384;
    big[b + j] = q0;        big[b + 64 + j] = q1;
    big[b + 128 + j] = kk0; big[b + 192 + j] = kk1;
    big[b + 256 + j] = v0;  big[b + 320 + j] = v1;
}

// ---------------- GAT scores: store exp + segment denominator ----------------
__global__ __launch_bounds__(256) void k_gat_sm13(const float* __restrict__ big,
                                                  const int* __restrict__ ei, int E,
                                                  float* __restrict__ scores,
                                                  float* __restrict__ sm) {
    long long t = (long long)blockIdx.x * 256 + threadIdx.x;
    if (t >= (long long)E * 8) return;
    int e = (int)(t >> 3), h = (int)(t & 7);
    int row = ei[e], col = ei[E + e];
    float s = 0.f;
    for (int d = 0; d < 16; ++d)
        s += big[(size_t)row * 384 + h * 16 + d] * big[(size_t)col * 384 + 128 + h * 16 + d];
    s *= 0.25f;
    s = s > 0.f ? s : 0.2f * s;
    float ex = expf(s);
    scores[t] = ex;
    atomicAdd(&sm[(size_t)col * 8 + h], ex);
}

// ---------------- GAT weighted-V scatter (reads stored probs) ----------------
__global__ __launch_bounds__(256) void k_gat_wv13(const float* __restrict__ big,
                                                  const int* __restrict__ ei, int E,
                                                  const float* __restrict__ scores,
                                                  const float* __restrict__ sm,
                                                  float* __restrict__ agg) {
    long long t = (long long)blockIdx.x * 256 + threadIdx.x;
    if (t >= (long long)E * 128) return;
    int e = (int)(t >> 7), j = (int)(t & 127);
    int row = ei[e], col = ei[E + e];
    int h = j >> 4;
    float p = scores[(size_t)e * 8 + h] / sm[(size_t)col * 8 + h];
    atomicAdd(&agg[(size_t)col * 128 + j], p * big[(size_t)row * 384 + 256 + j]);
}

// ---------------- GAT epilogue: obr = LN(agg@Wo + bo + x) ----------------
__global__ __launch_bounds__(64) void k_ep_gat13(const float* __restrict__ x,
                                                 const float* __restrict__ agg,
                                                 const float* __restrict__ Wo,
                                                 const float* __restrict__ bo,
                                                 const float* __restrict__ g,
                                                 const float* __restrict__ b,
                                                 float* __restrict__ obr) {
    __shared__ float buf[130];
    int i = blockIdx.x, j = threadIdx.x;
    float a0 = bo[j], a1 = bo[64 + j];
    for (int k = 0; k < 128; ++k) {
        float ak = agg[(size_t)i * 128 + k];
        a0 += ak * Wo[k * 128 + j];
        a1 += ak * Wo[k * 128 + 64 + j];
    }
    float v0 = a0 + x[(size_t)i * 128 + j];
    float v1 = a1 + x[(size_t)i * 128 + 64 + j];
    buf[j] = v0; buf[64 + j] = v1;
    __syncthreads();
    if (j == 0) {
        float s = 0.f;
        for (int k = 0; k < 128; ++k) s += buf[k];
        float m = s * 0.0078125f;
        float var = 0.f;
        for (int k = 0; k < 128; ++k) { float d = buf[k] - m; var += d * d; }
        buf[128] = m; buf[129] = rsqrtf(var * 0.0078125f + 1e-5f);
    }
    __syncthreads();
    float m = buf[128], r = buf[129];
    obr[(size_t)i * 128 + j]      = (v0 - m) * r * g[j]      + b[j];
    obr[(size_t)i * 128 + 64 + j] = (v1 - m) * r * g[64 + j] + b[64 + j];
}

// ---------------- per-type transform: h_gcn = x@Wt[t] + bt[t] ----------------
__global__ __launch_bounds__(64) void k_hgcn13(const float* __restrict__ x,
                                               const int* __restrict__ nt,
                                               const float* __restrict__ Wt,
                                               const float* __restrict__ bt,
                                               float* __restrict__ h_gcn) {
    int i = blockIdx.x, j = threadIdx.x;
    int t = nt[i];
    t = (t < 0 || t > 5) ? 0 : t;
    const float* W = Wt + (size_t)t * 16384;
    float a0 = bt[t * 128 + j], a1 = bt[t * 128 + 64 + j];
    for (int k = 0; k < 128; ++k) {
        float xa = x[(size_t)i * 128 + k];
        a0 += xa * W[k * 128 + j];
        a1 += xa * W[k * 128 + 64 + j];
    }
    h_gcn[(size_t)i * 128 + j] = a0;
    h_gcn[(size_t)i * 128 + 64 + j] = a1;
}

// ---------------- h_tmp = x + emb[clip(tpos)] ----------------
__global__ __launch_bounds__(256) void k_htmp13(const float* __restrict__ x,
                                                const float* __restrict__ emb,
                                                const int* __restrict__ tpos,
                                                float* __restrict__ h_tmp, int N) {
    long long t = (long long)blockIdx.x * 256 + threadIdx.x;
    if (t >= (long long)N * 128) return;
    int i = (int)(t >> 7), j = (int)(t & 127);
    int tp = tpos[i]; tp = tp < 0 ? 0 : (tp > 49 ? 49 : tp);
    h_tmp[t] = x[t] + emb[tp * 128 + j];
}

// ------- edge MLP (wave-batched): agg[col] += relu([h[row],h[col]]@W1+b1)@W2+b2 -------
// 512-thread blocks, 512 blocks -> 2 blocks/CU (LDS cap) = 16 waves/CU.
__global__ __launch_bounds__(512) void k_mlp_edge13(const float* __restrict__ h,
                                                    const int* __restrict__ ei, int E,
                                                    const float* __restrict__ W1,
                                                    const float* __restrict__ b1,
                                                    const float* __restrict__ W2,
                                                    const float* __restrict__ b2,
                                                    float* __restrict__ agg) {
    __shared__ float w1s[16384];  // W1 rows 0..127 (64 KB): the h[row] half of K
    for (int i = threadIdx.x; i < 16384; i += 512) w1s[i] = W1[i];
    __syncthreads();
    int l = threadIdx.x & 63;
    int wid = blockIdx.x * 8 + (threadIdx.x >> 6);
    int nw = gridDim.x * 8;
    float b1v0 = b1[l], b1v1 = b1[64 + l];
    float b2v0 = b2[l], b2v1 = b2[64 + l];
    for (int e0 = wid * 4; e0 < E; e0 += nw * 4) {
        int ne = E - e0; if (ne > 4) ne = 4;
        int colv[4];
        float zr[4][4];
#pragma unroll
        for (int n = 0; n < 4; ++n) {
            int e = e0 + ((n < ne) ? n : 0);
            int row = ei[e], col = ei[E + e];
            colv[n] = col;
            zr[n][0] = h[(size_t)row * 128 + l];
            zr[n][1] = h[(size_t)row * 128 + 64 + l];
            zr[n][2] = h[(size_t)col * 128 + l];
            zr[n][3] = h[(size_t)col * 128 + 64 + l];
        }
        float acc[4][2];
#pragma unroll
        for (int n = 0; n < 4; ++n) { acc[n][0] = b1v0; acc[n][1] = b1v1; }
        // layer 1: K=256. c=0,1 (h[row] features) from LDS; c=2,3 (h[col]) from L2.
#pragma unroll
        for (int c = 0; c < 4; ++c) {
#pragma unroll 8
            for (int k2 = 0; k2 < 64; ++k2) {
                int k = c * 64 + k2;
                float w0, w1v;
                if (c < 2) { w0 = w1s[k * 128 + l];          w1v = w1s[k * 128 + 64 + l]; }
                else       { w0 = W1[(size_t)k * 128 + l];   w1v = W1[(size_t)k * 128 + 64 + l]; }
#pragma unroll
                for (int n = 0; n < 4; ++n) {
                    float xk = __shfl(zr[n][c], k2);
                    acc[n][0] = fmaf(xk, w0, acc[n][0]);
                    acc[n][1] = fmaf(xk, w1v, acc[n][1]);
                }
            }
        }
        float z2[4][2];
#pragma unroll
        for (int n = 0; n < 4; ++n) {
            z2[n][0] = acc[n][0] > 0.f ? acc[n][0] : 0.f;
            z2[n][1] = acc[n][1] > 0.f ? acc[n][1] : 0.f;
        }
        float acc2[4][2];
#pragma unroll
        for (int n = 0; n < 4; ++n) { acc2[n][0] = b2v0; acc2[n][1] = b2v1; }
        // layer 2: K=128 from L2-resident W2
#pragma unroll
        for (int c = 0; c < 2; ++c) {
#pragma unroll 8
            for (int k2 = 0; k2 < 64; ++k2) {
                int k = c * 64 + k2;
                float w0 = W2[(size_t)k * 128 + l];
                float w1v = W2[(size_t)k * 128 + 64 + l];
#pragma unroll
                for (int n = 0; n < 4; ++n) {
                    float xk = __shfl(z2[n][c], k2);
                    acc2[n][0] = fmaf(xk, w0, acc2[n][0]);
                    acc2[n][1] = fmaf(xk, w1v, acc2[n][1]);
                }
            }
        }
#pragma unroll
        for (int n = 0; n < 4; ++n) {
            if (n < ne) {
                atomicAdd(&agg[(size_t)colv[n] * 128 + l], acc2[n][0]);
                atomicAdd(&agg[(size_t)colv[n] * 128 + 64 + l], acc2[n][1]);
            }
        }
    }
}

// ---------------- GCN epilogue ----------------
__global__ __launch_bounds__(64) void k_ep_gcn13(const float* __restrict__ x,
                                                 const float* __restrict__ h_gcn,
                                                 const float* __restrict__ agg,
                                                 const float* __restrict__ aW1,
                                                 const float* __restrict__ ab1,
                                                 const float* __restrict__ aW2,
                                                 const float* __restrict__ ab2,
                                                 const float* __restrict__ Wo,
                                                 const float* __restrict__ bo,
                                                 const float* __restrict__ g,
                                                 const float* __restrict__ b,
                                                 float* __restrict__ obr) {
    __shared__ float u[128];
    __shared__ float z3[128];
    __shared__ float buf[130];
    int i = blockIdx.x, j = threadIdx.x;
    float a0 = ab1[j], a1 = ab1[64 + j];
    for (int k = 0; k < 128; ++k) {
        float ak = agg[(size_t)i * 128 + k];
        a0 += ak * aW1[k * 128 + j];
        a1 += ak * aW1[k * 128 + 64 + j];
    }
    u[j] = a0 > 0.f ? a0 : 0.f;
    u[64 + j] = a1 > 0.f ? a1 : 0.f;
    __syncthreads();
    float c0 = ab2[j], c1 = ab2[64 + j];
    for (int k = 0; k < 128; ++k) {
        float uk = u[k];
        c0 += uk * aW2[k * 128 + j];
        c1 += uk * aW2[k * 128 + 64 + j];
    }
    z3[j] = c0 + h_gcn[(size_t)i * 128 + j];
    z3[64 + j] = c1 + h_gcn[(size_t)i * 128 + 64 + j];
    __syncthreads();
    float d0 = bo[j], d1 = bo[64 + j];
    for (int k = 0; k < 128; ++k) {
        float zk = z3[k];
        d0 += zk * Wo[k * 128 + j];
        d1 += zk * Wo[k * 128 + 64 + j];
    }
    float v0 = d0 + x[(size_t)i * 128 + j];
    float v1 = d1 + x[(size_t)i * 128 + 64 + j];
    buf[j] = v0; buf[64 + j] = v1;
    __syncthreads();
    if (j == 0) {
        float s = 0.f;
        for (int k = 0; k < 128; ++k) s += buf[k];
        float m = s * 0.0078125f;
        float var = 0.f;
        for (int k = 0; k < 128; ++k) { float d = buf[k] - m; var += d * d; }
        buf[128] = m; buf[129] = rsqrtf(var * 0.0078125f + 1e-5f);
    }
    __syncthreads();
    float m = buf[128], r = buf[129];
    obr[(size_t)i * 128 + j]      = (v0 - m) * r * g[j]      + b[j];
    obr[(size_t)i * 128 + 64 + j] = (v1 - m) * r * g[64 + j] + b[64 + j];
}

// ---------------- temporal epilogue ----------------
__global__ __launch_bounds__(64) void k_ep_tmp13(const float* __restrict__ h_tmp,
                                                 const float* __restrict__ agg,
                                                 const float* __restrict__ Wo,
                                                 const float* __restrict__ bo,
                                                 const float* __restrict__ g,
                                                 const float* __restrict__ b,
                                                 float* __restrict__ obr) {
    __shared__ float z[128];
    __shared__ float buf[130];
    int i = blockIdx.x, j = threadIdx.x;
    z[j]      = h_tmp[(size_t)i * 128 + j]      + agg[(size_t)i * 128 + j];
    z[64 + j] = h_tmp[(size_t)i * 128 + 64 + j] + agg[(size_t)i * 128 + 64 + j];
    __syncthreads();
    float a0 = bo[j], a1 = bo[64 + j];
    for (int k = 0; k < 128; ++k) {
        float zk = z[k];
        a0 += zk * Wo[k * 128 + j];
        a1 += zk * Wo[k * 128 + 64 + j];
    }
    buf[j] = a0; buf[64 + j] = a1;
    __syncthreads();
    if (j == 0) {
        float s = 0.f;
        for (int k = 0; k < 128; ++k) s += buf[k];
        float m = s * 0.0078125f;
        float var = 0.f;
        for (int k = 0; k < 128; ++k) { float d = buf[k] - m; var += d * d; }
        buf[128] = m; buf[129] = rsqrtf(var * 0.0078125f + 1e-5f);
    }
    __syncthreads();
    float m = buf[128], r = buf[129];
    obr[(size_t)i * 128 + j]      = (a0 - m) * r * g[j]      + b[j];
    obr[(size_t)i * 128 + 64 + j] = (a1 - m) * r * g[64 + j] + b[64 + j];
}

// ---------------- fusion accumulate ----------------
__global__ __launch_bounds__(64) void k_fuse13(const float* __restrict__ obr,
                                               const float* __restrict__ fusW,
                                               const float* __restrict__ fus_b,
                                               float* __restrict__ fused, int off, int first) {
    int i = blockIdx.x, j = threadIdx.x;
    float a0 = first ? fus_b[j]      : fused[(size_t)i * 128 + j];
    float a1 = first ? fus_b[64 + j] : fused[(size_t)i * 128 + 64 + j];
    for (int k = 0; k < 128; ++k) {
        float ok = obr[(size_t)i * 128 + k];
        a0 += ok * fusW[(size_t)(off + k) * 128 + j];
        a1 += ok * fusW[(size_t)(off + k) * 128 + 64 + j];
    }
    fused[(size_t)i * 128 + j] = a0;
    fused[(size_t)i * 128 + 64 + j] = a1;
}

// ---------------- final LN -> float32 out ----------------
__global__ __launch_bounds__(64) void k_final13(const float* __restrict__ fused,
                                                const float* __restrict__ g,
                                                const float* __restrict__ b,
                                                float* __restrict__ out) {
    __shared__ float buf[130];
    int i = blockIdx.x, j = threadIdx.x;
    float v0 = fused[(size_t)i * 128 + j];
    float v1 = fused[(size_t)i * 128 + 64 + j];
    buf[j] = v0; buf[64 + j] = v1;
    __syncthreads();
    if (j == 0) {
        float s = 0.f;
        for (int k = 0; k < 128; ++k) s += buf[k];
        float m = s * 0.0078125f;
        float var = 0.f;
        for (int k = 0; k < 128; ++k) { float d = buf[k] - m; var += d * d; }
        buf[128] = m; buf[129] = rsqrtf(var * 0.0078125f + 1e-5f);
    }
    __syncthreads();
    float m = buf[128], r = buf[129];
    out[(size_t)i * 128 + j]      = (v0 - m) * r * g[j]      + b[j];
    out[(size_t)i * 128 + 64 + j] = (v1 - m) * r * g[64 + j] + b[64 + j];
}

extern "C" void kernel_launch(void* const* d_in, const int* in_sizes, int n_in, void* d_out,
                              int out_size, void* d_ws, size_t ws_size, hipStream_t stream) {
    (void)n_in; (void)out_size; (void)ws_size;
    const float* x = (const float*)d_in[0];
    const float* gat_Wq = (const float*)d_in[4];
    const float* gat_Wk = (const float*)d_in[5];
    const float* gat_Wv = (const float*)d_in[6];
    const float* gat_Wo = (const float*)d_in[7];
    const float* gat_bo = (const float*)d_in[8];
    const float* gat_g = (const float*)d_in[9];
    const float* gat_b = (const float*)d_in[10];
    const float* gcn_Wt = (const float*)d_in[11];
    const float* gcn_bt = (const float*)d_in[12];
    const float* gcn_mW1 = (const float*)d_in[13];
    const float* gcn_mb1 = (const float*)d_in[14];
    const float* gcn_mW2 = (const float*)d_in[15];
    const float* gcn_mb2 = (const float*)d_in[16];
    const float* gcn_aW1 = (const float*)d_in[17];
    const float* gcn_ab1 = (const float*)d_in[18];
    const float* gcn_aW2 = (const float*)d_in[19];
    const float* gcn_ab2 = (const float*)d_in[20];
    const float* gcn_Wo = (const float*)d_in[21];
    const float* gcn_bo = (const float*)d_in[22];
    const float* gcn_g = (const float*)d_in[23];
    const float* gcn_b = (const float*)d_in[24];
    const float* tmp_emb = (const float*)d_in[25];
    const float* tmp_W1 = (const float*)d_in[26];
    const float* tmp_b1 = (const float*)d_in[27];
    const float* tmp_W2 = (const float*)d_in[28];
    const float* tmp_b2 = (const float*)d_in[29];
    const float* tmp_Wo = (const float*)d_in[30];
    const float* tmp_bo = (const float*)d_in[31];
    const float* tmp_g = (const float*)d_in[32];
    const float* tmp_b = (const float*)d_in[33];
    const float* fus_W = (const float*)d_in[34];
    const float* fus_b = (const float*)d_in[35];
    const float* fus_g = (const float*)d_in[36];
    const float* fus_be = (const float*)d_in[37];

    int N = in_sizes[0] / 128;
    int E = in_sizes[1] / 2;

    // ---- workspace ----
    float* ws = (float*)d_ws;
    float* big = ws;                          // [0,384N): QKV during GAT phase
    float* fused = ws;                        // [0,128N): alias after QKV dead
    float* h_gcn = ws + (size_t)128 * N;      // [128N,256N): alias after QKV dead
    float* h_tmp = ws + (size_t)256 * N;      // [256N,384N): alias after QKV dead
    float* obr = ws + (size_t)384 * N;        // [384N,512N)
    float* agg = ws + (size_t)512 * N;        // [512N,640N)
    float* sm = ws + (size_t)640 * N;         // [640N,648N)
    u32* flags = (u32*)(ws + (size_t)648 * N);
    int* ei32 = (int*)(flags + 16);
    int* nt32 = ei32 + (size_t)2 * E;
    int* tp32 = nt32 + N;
    float* scores = (float*)(tp32 + N);       // E*8 floats

    // ---- index canonicalization (planar (2,E) layout) ----
    k_detect13<<<1, 64, 0, stream>>>((const u32*)d_in[1], (const u32*)d_in[2],
                                     (const u32*)d_in[3], flags);
    long long nEI = (long long)2 * E;
    k_cvt13<<<(int)((nEI + 255) / 256), 256, 0, stream>>>(d_in[1], ei32, nEI, flags, 0);
    k_cvt13<<<(N + 255) / 256, 256, 0, stream>>>(d_in[2], nt32, N, flags, 1);
    k_cvt13<<<(N + 255) / 256, 256, 0, stream>>>(d_in[3], tp32, N, flags, 2);

    long long nAgg = (long long)128 * N, nAggSm = (long long)136 * N;
    int gAggSm = (int)((nAggSm + 255) / 256), gAgg = (int)((nAgg + 255) / 256);
    int gE8 = (int)(((long long)E * 8 + 255) / 256);
    int gE128 = (int)(((long long)E * 128 + 255) / 256);
    int gN128 = (int)(((long long)N * 128 + 255) / 256);

    // ===== GAT branch =====
    kz13<<<gAggSm, 256, 0, stream>>>(agg, nAggSm);                   // zero agg + sm
    k_qkv13<<<N, 64, 0, stream>>>(x, gat_Wq, gat_Wk, gat_Wv, big);
    k_gat_sm13<<<gE8, 256, 0, stream>>>(big, ei32, E, scores, sm);
    k_gat_wv13<<<gE128, 256, 0, stream>>>(big, ei32, E, scores, sm, agg);
    k_ep_gat13<<<N, 64, 0, stream>>>(x, agg, gat_Wo, gat_bo, gat_g, gat_b, obr);
    k_fuse13<<<N, 64, 0, stream>>>(obr, fus_W, fus_b, fused, 0, 1);  // QKV dead; overwrite OK

    // ===== GCN branch =====
    k_hgcn13<<<N, 64, 0, stream>>>(x, nt32, gcn_Wt, gcn_bt, h_gcn);
    kz13<<<gAgg, 256, 0, stream>>>(agg, nAgg);
    k_mlp_edge13<<<512, 512, 0, stream>>>(h_gcn, ei32, E, gcn_mW1, gcn_mb1, gcn_mW2, gcn_mb2, agg);
    k_ep_gcn13<<<N, 64, 0, stream>>>(x, h_gcn, agg, gcn_aW1, gcn_ab1, gcn_aW2, gcn_ab2,
                                     gcn_Wo, gcn_bo, gcn_g, gcn_b, obr);
    k_fuse13<<<N, 64, 0, stream>>>(obr, fus_W, fus_b, fused, 128, 0);

    // ===== temporal branch =====
    k_htmp13<<<gN128, 256, 0, stream>>>(x, tmp_emb, tp32, h_tmp, N);
    kz13<<<gAgg, 256, 0, stream>>>(agg, nAgg);
    k_mlp_edge13<<<512, 512, 0, stream>>>(h_tmp, ei32, E, tmp_W1, tmp_b1, tmp_W2, tmp_b2, agg);
    k_ep_tmp13<<<N, 64, 0, stream>>>(h_tmp, agg, tmp_Wo, tmp_bo, tmp_g, tmp_b, obr);
    k_fuse13<<<N, 64, 0, stream>>>(obr, fus_W, fus_b, fused, 256, 0);

    // ===== final (float32 output) =====
    k_final13<<<N, 64, 0, stream>>>(fused, fus_g, fus_be, (float*)d_out);
}